// Round 10
// baseline (503.569 us; speedup 1.0000x reference)
//
#include <hip/hip_runtime.h>
#include <hip/hip_bf16.h>

typedef __attribute__((ext_vector_type(8))) short short8;
typedef __attribute__((ext_vector_type(8))) _Float16 half8;
typedef __attribute__((ext_vector_type(4))) float f32x4;

#define NROWS 32768
#define CDIM 1024
#define BNC 256
#define TOPK 128
#define NKT 32   // k_main K-tiles of 32

struct alignas(8) U4 { unsigned short x, y, z, w; };

__device__ __forceinline__ unsigned short f2bf(float f){
  union { float f; unsigned u; } v; v.f = f;
  unsigned r = v.u + 0x7FFFu + ((v.u >> 16) & 1u);
  return (unsigned short)(r >> 16);
}
__device__ __forceinline__ float bf2f(unsigned short h){
  union { unsigned u; float f; } v; v.u = ((unsigned)h) << 16;
  return v.f;
}
__device__ __forceinline__ unsigned short f2h(float f){
  _Float16 h = (_Float16)f;
  union { _Float16 h; unsigned short u; } v; v.h = h; return v.u;
}
__device__ __forceinline__ float h2f(unsigned short u){
  union { unsigned short u; _Float16 h; } v; v.u = u; return (float)v.h;
}
__device__ __forceinline__ void gl16(const void* g, void* l){
  __builtin_amdgcn_global_load_lds((const __attribute__((address_space(1))) void*)g,
                                   (__attribute__((address_space(3))) void*)l, 16, 0, 0);
}
__device__ __forceinline__ unsigned ldsaddr(const void* p){
  return (unsigned)(uintptr_t)(const __attribute__((address_space(3))) void*)p;
}
// asm ds_read_b128: invisible to the waitcnt pass -> no auto vmcnt drains against
// outstanding global_load_lds. Correctness: explicit lgkmcnt(0) + sched_barrier(0)
// before the consuming MFMAs (rule #18).
__device__ __forceinline__ short8 dsr128(unsigned addr){
  short8 r;
  asm volatile("ds_read_b128 %0, %1" : "=v"(r) : "v"(addr));
  return r;
}
__device__ __forceinline__ half8 s2h(short8 s){ union { short8 s; half8 h; } u; u.s = s; return u.h; }

// XOR swizzle within rows of 64B (4 granules of 16B): granule g -> g ^ swzf(r).
// Involution: pre-swizzle global source at stage, swizzle offset at read. 2-way = free.
__device__ __forceinline__ int swzf(int r){ return (r & 3) ^ ((r >> 2) & 1); }
__device__ __forceinline__ int swz(int o){ return o ^ (swzf(o >> 6) << 4); }

// stage one [128 rows][32 k] tile (8 KB) into LDS (256-thread blocks)
__device__ __forceinline__ void stage_tile(const unsigned short* g0, int gstride,
                                           char* lds, int tid){
  #pragma unroll
  for (int i = 0; i < 2; ++i){
    int o = tid * 16 + i * 4096;
    int lb = swz(o);
    gl16((const char*)g0 + (lb >> 6) * gstride + (lb & 63), lds + o);
  }
}
__device__ __forceinline__ int frag_off(int ridx, int lane){
  return ridx * 64 + (((lane >> 4) ^ swzf(ridx)) << 4);
}

// ---------------- param prep ----------------
__global__ void k_wt(const float* __restrict__ W, unsigned short* __restrict__ Wt){
  __shared__ float t[32][33];
  int tx = threadIdx.x, ty = threadIdx.y;
  int bx = blockIdx.x * 32, by = blockIdx.y * 32;
  for (int i = ty; i < 32; i += 8)
    t[i][tx] = W[(by + i) * CDIM + bx + tx];
  __syncthreads();
  for (int i = ty; i < 32; i += 8)
    Wt[(bx + i) * CDIM + by + tx] = f2h(t[tx][i]);
}

__global__ void k_ecast(const float* __restrict__ eo, const float* __restrict__ ei,
                        unsigned short* __restrict__ ho, unsigned short* __restrict__ hi){
  int i = blockIdx.x * 256 + threadIdx.x;
  ho[i] = f2h(eo[i]);
  hi[i] = f2h(ei[i]);
}

// ---------------- bottleneck: grouped conv + BN + GELU (fp16 out), plus x->fp16 ----------------
__global__ __launch_bounds__(256) void k_bottleneck(
    const float* __restrict__ x,
    const float* __restrict__ cwo, const float* __restrict__ cbo,
    const float* __restrict__ go,  const float* __restrict__ bto,
    const float* __restrict__ mo,  const float* __restrict__ vo,
    const float* __restrict__ cwi, const float* __restrict__ cbi,
    const float* __restrict__ gi,  const float* __restrict__ bti,
    const float* __restrict__ mi,  const float* __restrict__ vi,
    unsigned short* __restrict__ x16,
    unsigned short* __restrict__ uo, unsigned short* __restrict__ ui)
{
  const int t = threadIdx.x;
  const int r0 = blockIdx.x * 8;
  float4 cwov = ((const float4*)cwo)[t];
  float4 cwiv = ((const float4*)cwi)[t];
  float sco = go[t] * rsqrtf(vo[t] + 1e-5f);
  float sho = bto[t] - mo[t] * sco;
  float cbov = cbo[t];
  float sci = gi[t] * rsqrtf(vi[t] + 1e-5f);
  float shi = bti[t] - mi[t] * sci;
  float cbiv = cbi[t];
  for (int r = 0; r < 8; ++r){
    int row = r0 + r;
    float4 xv = ((const float4*)x)[row * 256 + t];
    U4 xb; xb.x = f2h(xv.x); xb.y = f2h(xv.y); xb.z = f2h(xv.z); xb.w = f2h(xv.w);
    ((U4*)x16)[row * 256 + t] = xb;
    float h = xv.x*cwov.x + xv.y*cwov.y + xv.z*cwov.z + xv.w*cwov.w + cbov;
    h = h * sco + sho;
    float u = 0.5f * h * (1.0f + erff(h * 0.70710678118654752f));
    uo[row*BNC + t] = f2h(u);
    h = xv.x*cwiv.x + xv.y*cwiv.y + xv.z*cwiv.z + xv.w*cwiv.w + cbiv;
    h = h * sci + shi;
    u = 0.5f * h * (1.0f + erff(h * 0.70710678118654752f));
    ui[row*BNC + t] = f2h(u);
  }
}

// ---------------- expand GEMM (fp16): L = U@E^T + eb -> fp16 Lbuf ----------------
__global__ __launch_bounds__(256, 3) void k_expand(
    const unsigned short* __restrict__ u16, const unsigned short* __restrict__ e16,
    const float* __restrict__ eb, unsigned short* __restrict__ Lout)
{
  __shared__ alignas(16) char lds[3 * 16384];
  const int tid = threadIdx.x;
  const int lane = tid & 63, w = tid >> 6;
  const int wr = (w >> 1) * 64, wc = (w & 1) * 64;
  int id = blockIdx.x;
  int xcd = id & 7, slot = id >> 3;
  const int row0 = (xcd * 32 + (slot >> 3)) * 128;
  const int col0 = (slot & 7) * 128;
  f32x4 acc[4][4] = {};
  auto stage = [&](int h, int buf){
    char* b = lds + buf * 16384;
    stage_tile(u16 + row0 * BNC + h * 32, 512, b, tid);
    stage_tile(e16 + col0 * BNC + h * 32, 512, b + 8192, tid);
  };
  stage(0, 0);
  stage(1, 1);
  asm volatile("s_waitcnt vmcnt(4)" ::: "memory");
  __builtin_amdgcn_s_barrier();
  const unsigned lbase = ldsaddr(lds);
  const int NK = BNC / 32;
  for (int h = 0; h < NK; ++h){
    unsigned sl = lbase + (h % 3) * 16384;
    short8 af[4], bfr[4];
    #pragma unroll
    for (int m = 0; m < 4; ++m) af[m]  = dsr128(sl + frag_off(wr + m * 16 + (lane & 15), lane));
    #pragma unroll
    for (int n = 0; n < 4; ++n) bfr[n] = dsr128(sl + 8192 + frag_off(wc + n * 16 + (lane & 15), lane));
    if (h + 2 < NK) stage(h + 2, (h + 2) % 3);
    __builtin_amdgcn_s_barrier();
    asm volatile("s_waitcnt lgkmcnt(0)" ::: "memory");
    __builtin_amdgcn_sched_barrier(0);
    __builtin_amdgcn_s_setprio(1);
    #pragma unroll
    for (int m = 0; m < 4; ++m)
      #pragma unroll
      for (int n = 0; n < 4; ++n)
        acc[m][n] = __builtin_amdgcn_mfma_f32_16x16x32_f16(s2h(af[m]), s2h(bfr[n]), acc[m][n], 0, 0, 0);
    __builtin_amdgcn_s_setprio(0);
    if (h + 2 < NK)      asm volatile("s_waitcnt vmcnt(4)" ::: "memory");
    else if (h + 1 < NK) asm volatile("s_waitcnt vmcnt(0)" ::: "memory");
    __builtin_amdgcn_s_barrier();
  }
  #pragma unroll
  for (int n = 0; n < 4; ++n){
    int col = col0 + wc + n * 16 + (lane & 15);
    float ebv = eb[col];
    #pragma unroll
    for (int m = 0; m < 4; ++m){
      int row = row0 + wr + m * 16 + ((lane >> 4) << 2);
      #pragma unroll
      for (int r = 0; r < 4; ++r)
        Lout[(size_t)(row + r) * CDIM + col] = f2h(acc[m][n][r] + ebv);
    }
  }
}

// ---------------- softmax + top-128 threshold + sparse score (fp16 L) ----------------
template<bool WRITE_XS>
__global__ __launch_bounds__(256) void k_select(
    const unsigned short* __restrict__ Lg, const unsigned short* __restrict__ xg,
    unsigned short* __restrict__ obf)
{
  const int lane = threadIdx.x & 63;
  const int wv = threadIdx.x >> 6;
  int id = blockIdx.x;
  int xcd = id & 7, rest = id >> 3;
  int q = rest >> 5, b = rest & 31;
  const int row = (xcd * 32 + q) * 128 + b * 4 + wv;
  const unsigned short* Lr = Lg + (size_t)row * CDIM;
  unsigned short hv[16];
  #pragma unroll
  for (int c = 0; c < 2; ++c){
    short8 t8 = ((const short8*)Lr)[c * 64 + lane];
    #pragma unroll
    for (int j = 0; j < 8; ++j) hv[c*8+j] = (unsigned short)t8[j];
  }
  unsigned kx[16];
  #pragma unroll
  for (int j = 0; j < 16; ++j){
    unsigned u = hv[j];
    kx[j] = u ^ ((u & 0x8000u) ? 0xFFFFu : 0x8000u);
  }
  float v[16];
  #pragma unroll
  for (int j = 0; j < 16; ++j) v[j] = h2f(hv[j]);
  float M = v[0];
  #pragma unroll
  for (int j = 1; j < 16; ++j) M = fmaxf(M, v[j]);
  #pragma unroll
  for (int off = 32; off > 0; off >>= 1) M = fmaxf(M, __shfl_xor(M, off));
  float e[16];
  float S = 0.f;
  #pragma unroll
  for (int j = 0; j < 16; ++j){ e[j] = expf(v[j] - M); S += e[j]; }
  #pragma unroll
  for (int off = 32; off > 0; off >>= 1) S += __shfl_xor(S, off);
  unsigned pref = 0;
  for (int bit = 15; bit >= 0; --bit){
    unsigned cand = pref | (1u << bit);
    int c = 0;
    #pragma unroll
    for (int j = 0; j < 16; ++j)
      c += (int)__popcll(__ballot(kx[j] >= cand));
    if (c >= TOPK) pref = cand;
  }
  float invS = 1.0f / S;
  #pragma unroll
  for (int c = 0; c < 2; ++c){
    unsigned short o8[8];
    if (WRITE_XS){
      short8 xv = ((const short8*)(xg + (size_t)row * CDIM))[c * 64 + lane];
      #pragma unroll
      for (int j = 0; j < 8; ++j){
        int jj = c*8 + j;
        float scf = (kx[jj] >= pref) ? e[jj] * invS : 0.f;
        o8[j] = f2h(h2f((unsigned short)xv[j]) * scf);
      }
    } else {
      #pragma unroll
      for (int j = 0; j < 8; ++j){
        int jj = c*8 + j;
        float sc = (kx[jj] >= pref) ? e[jj] * invS : 0.f;
        o8[j] = f2h(sc);
      }
    }
    short8 st;
    #pragma unroll
    for (int j = 0; j < 8; ++j) st[j] = (short)o8[j];
    ((short8*)(obf + (size_t)row * CDIM))[c * 64 + lane] = st;
  }
}

// ---------------- main dual-A GEMM: A in registers, B-only LDS (3-slot lead-2) --------
// 256 thr / 4 waves, tile 128x128, fp16. A1/A2 frags load straight global->VGPR
// (L2-resident panels via XCD remap); LDS holds only B (3 x 8 KB). Per kt each thread
// issues 8 A-loads + 2 B-stage gl16; end-of-kt vmcnt(2) leaves only B-stage(kt+2)
// outstanding -> B(kt+1) published at the barrier. A-reg deps are compiler-tracked.
// Tail: kt==30 -> vmcnt(0); kt==31 no wait. Ping-pong A arrays via kt+=2 (rule #20).
__global__ __launch_bounds__(256, 2) void k_main(
    const unsigned short* __restrict__ x16, const unsigned short* __restrict__ xs16,
    const unsigned short* __restrict__ wt,  const unsigned short* __restrict__ so16,
    const float* __restrict__ bias, float* __restrict__ out)
{
  __shared__ alignas(16) char lds[3 * 8192];
  const int tid = threadIdx.x;
  const int lane = tid & 63, w = tid >> 6;
  const int wr = (w >> 1) * 64, wc = (w & 1) * 64;
  int id = blockIdx.x;
  int xcd = id & 7, sl = id >> 3;
  const int row0 = (xcd * 32 + (sl >> 3)) * 128;
  const int col0 = (sl & 7) * 128;
  f32x4 acc1[4][4] = {}, acc2[4][4] = {};
  const unsigned lbase = ldsaddr(lds);

  auto stageB = [&](int kt){
    char* slot = lds + (kt % 3) * 8192;
    stage_tile(wt + col0 * CDIM + kt * 32, 2048, slot, tid);
  };
  auto loadA = [&](int kt, short8 (&d1)[4], short8 (&d2)[4]){
    #pragma unroll
    for (int m = 0; m < 4; ++m){
      size_t o = (size_t)(row0 + wr + m * 16 + (lane & 15)) * CDIM
               + (size_t)kt * 32 + ((lane >> 4) << 3);
      d1[m] = *(const short8*)(x16 + o);
      d2[m] = *(const short8*)(xs16 + o);
    }
  };

  short8 aA1[4], aA2[4], aB1[4], aB2[4];
  loadA(0, aA1, aA2);
  stageB(0);
  stageB(1);
  asm volatile("s_waitcnt vmcnt(2)" ::: "memory");
  __builtin_amdgcn_s_barrier();

  auto body = [&](int kt, short8 (&c1)[4], short8 (&c2)[4],
                  short8 (&n1)[4], short8 (&n2)[4]){
    const unsigned slr = lbase + (kt % 3) * 8192;
    short8 bfr[4];
    #pragma unroll
    for (int n = 0; n < 4; ++n)
      bfr[n] = dsr128(slr + frag_off(wc + n * 16 + (lane & 15), lane));
    if (kt + 1 < NKT) loadA(kt + 1, n1, n2);
    if (kt + 2 < NKT) stageB(kt + 2);
    asm volatile("s_waitcnt lgkmcnt(0)" ::: "memory");
    __builtin_amdgcn_sched_barrier(0);
    __builtin_amdgcn_s_setprio(1);
    #pragma unroll
    for (int m = 0; m < 4; ++m)
      #pragma unroll
      for (int n = 0; n < 4; ++n){
        acc1[m][n] = __builtin_amdgcn_mfma_f32_16x16x32_f16(s2h(c1[m]), s2h(bfr[n]), acc1[m][n], 0, 0, 0);
        acc2[m][n] = __builtin_amdgcn_mfma_f32_16x16x32_f16(s2h(c2[m]), s2h(bfr[n]), acc2[m][n], 0, 0, 0);
      }
    __builtin_amdgcn_s_setprio(0);
    if (kt + 2 < NKT)      asm volatile("s_waitcnt vmcnt(2)" ::: "memory");
    else if (kt + 1 < NKT) asm volatile("s_waitcnt vmcnt(0)" ::: "memory");
    __builtin_amdgcn_s_barrier();
  };

  for (int kt = 0; kt < NKT; kt += 2){
    body(kt,     aA1, aA2, aB1, aB2);
    body(kt + 1, aB1, aB2, aA1, aA2);
  }

  #pragma unroll
  for (int n = 0; n < 4; ++n){
    int col = col0 + wc + n * 16 + (lane & 15);
    float bv = bias[col];
    #pragma unroll
    for (int m = 0; m < 4; ++m){
      int row = row0 + wr + m * 16 + ((lane >> 4) << 2);
      #pragma unroll
      for (int r = 0; r < 4; ++r){
        float so = h2f(so16[(size_t)(row + r) * CDIM + col]);
        out[(size_t)(row + r) * CDIM + col] = acc1[m][n][r] * so + acc2[m][n][r] + bv;
      }
    }
  }
}

extern "C" void kernel_launch(void* const* d_in, const int* in_sizes, int n_in,
                              void* d_out, int out_size, void* d_ws, size_t ws_size,
                              hipStream_t stream)
{
  const float* x    = (const float*)d_in[0];
  const float* W    = (const float*)d_in[1];
  const float* bias = (const float*)d_in[2];
  const float* cwo  = (const float*)d_in[3];
  const float* cbo  = (const float*)d_in[4];
  const float* bngo = (const float*)d_in[5];
  const float* bnbo = (const float*)d_in[6];
  const float* bnmo = (const float*)d_in[7];
  const float* bnvo = (const float*)d_in[8];
  const float* ewo  = (const float*)d_in[9];
  const float* ebo  = (const float*)d_in[10];
  const float* cwi  = (const float*)d_in[11];
  const float* cbi  = (const float*)d_in[12];
  const float* bngi = (const float*)d_in[13];
  const float* bnbi = (const float*)d_in[14];
  const float* bnmi = (const float*)d_in[15];
  const float* bnvi = (const float*)d_in[16];
  const float* ewi  = (const float*)d_in[17];
  const float* ebi  = (const float*)d_in[18];
  float* out = (float*)d_out;
  (void)in_sizes; (void)n_in; (void)out_size; (void)ws_size;

  char* ws = (char*)d_ws;
  size_t off = 0;
  auto alloc = [&](size_t bytes){ void* p = ws + off; off += (bytes + 255) & ~(size_t)255; return p; };
  unsigned short* x16  = (unsigned short*)alloc((size_t)NROWS * CDIM * 2);
  unsigned short* xs16 = (unsigned short*)alloc((size_t)NROWS * CDIM * 2);
  unsigned short* so16 = (unsigned short*)alloc((size_t)NROWS * CDIM * 2);
  unsigned short* Lbuf = (unsigned short*)alloc((size_t)NROWS * CDIM * 2);
  unsigned short* uo   = (unsigned short*)alloc((size_t)NROWS * BNC * 2);
  unsigned short* ui   = (unsigned short*)alloc((size_t)NROWS * BNC * 2);
  unsigned short* wtb  = (unsigned short*)alloc((size_t)CDIM * CDIM * 2);
  unsigned short* e16o = (unsigned short*)alloc((size_t)CDIM * BNC * 2);
  unsigned short* e16i = (unsigned short*)alloc((size_t)CDIM * BNC * 2);

  k_wt<<<dim3(32, 32), dim3(32, 8), 0, stream>>>(W, wtb);
  k_ecast<<<dim3(1024), dim3(256), 0, stream>>>(ewo, ewi, e16o, e16i);
  k_bottleneck<<<dim3(NROWS / 8), dim3(256), 0, stream>>>(
      x, cwo, cbo, bngo, bnbo, bnmo, bnvo,
      cwi, cbi, bngi, bnbi, bnmi, bnvi, x16, uo, ui);
  k_expand<<<dim3(2048), dim3(256), 0, stream>>>(uo, e16o, ebo, Lbuf);
  k_select<false><<<dim3(NROWS / 4), dim3(256), 0, stream>>>(Lbuf, nullptr, so16);
  k_expand<<<dim3(2048), dim3(256), 0, stream>>>(ui, e16i, ebi, Lbuf);
  k_select<true><<<dim3(NROWS / 4), dim3(256), 0, stream>>>(Lbuf, x16, xs16);
  k_main<<<dim3(2048), dim3(256), 0, stream>>>(x16, xs16, wtb, so16, bias, out);
}

// Round 11
// 366.789 us; speedup vs baseline: 1.3729x; 1.3729x over previous
//
#include <hip/hip_runtime.h>
#include <hip/hip_bf16.h>

typedef __attribute__((ext_vector_type(8))) short short8;
typedef __attribute__((ext_vector_type(8))) _Float16 half8;
typedef __attribute__((ext_vector_type(4))) float f32x4;

#define NROWS 32768
#define CDIM 1024
#define BNC 256
#define TOPK 128
#define NKT 32   // k_main K-tiles of 32

struct alignas(8) U4 { unsigned short x, y, z, w; };

__device__ __forceinline__ unsigned short f2bf(float f){
  union { float f; unsigned u; } v; v.f = f;
  unsigned r = v.u + 0x7FFFu + ((v.u >> 16) & 1u);
  return (unsigned short)(r >> 16);
}
__device__ __forceinline__ float bf2f(unsigned short h){
  union { unsigned u; float f; } v; v.u = ((unsigned)h) << 16;
  return v.f;
}
__device__ __forceinline__ unsigned short f2h(float f){
  _Float16 h = (_Float16)f;
  union { _Float16 h; unsigned short u; } v; v.h = h; return v.u;
}
__device__ __forceinline__ float h2f(unsigned short u){
  union { unsigned short u; _Float16 h; } v; v.u = u; return (float)v.h;
}
__device__ __forceinline__ void gl16(const void* g, void* l){
  __builtin_amdgcn_global_load_lds((const __attribute__((address_space(1))) void*)g,
                                   (__attribute__((address_space(3))) void*)l, 16, 0, 0);
}
__device__ __forceinline__ unsigned ldsaddr(const void* p){
  return (unsigned)(uintptr_t)(const __attribute__((address_space(3))) void*)p;
}
// asm ds_read_b128: invisible to the waitcnt pass -> no auto vmcnt drains against
// outstanding global_load_lds. Correctness: explicit lgkmcnt(0) + sched_barrier(0)
// before the consuming MFMAs (rule #18).
__device__ __forceinline__ short8 dsr128(unsigned addr){
  short8 r;
  asm volatile("ds_read_b128 %0, %1" : "=v"(r) : "v"(addr));
  return r;
}
__device__ __forceinline__ half8 s2h(short8 s){ union { short8 s; half8 h; } u; u.s = s; return u.h; }

// XOR swizzle within rows of 64B (4 granules of 16B): granule g -> g ^ swzf(r).
// Involution: pre-swizzle global source at stage, swizzle offset at read. 2-way = free.
__device__ __forceinline__ int swzf(int r){ return (r & 3) ^ ((r >> 2) & 1); }
__device__ __forceinline__ int swz(int o){ return o ^ (swzf(o >> 6) << 4); }

// stage one [128 rows][32 k] tile (8 KB) into LDS (256-thread blocks)
__device__ __forceinline__ void stage_tile(const unsigned short* g0, int gstride,
                                           char* lds, int tid){
  #pragma unroll
  for (int i = 0; i < 2; ++i){
    int o = tid * 16 + i * 4096;
    int lb = swz(o);
    gl16((const char*)g0 + (lb >> 6) * gstride + (lb & 63), lds + o);
  }
}
__device__ __forceinline__ int frag_off(int ridx, int lane){
  return ridx * 64 + (((lane >> 4) ^ swzf(ridx)) << 4);
}

// ---------------- param prep ----------------
__global__ void k_wt(const float* __restrict__ W, unsigned short* __restrict__ Wt){
  __shared__ float t[32][33];
  int tx = threadIdx.x, ty = threadIdx.y;
  int bx = blockIdx.x * 32, by = blockIdx.y * 32;
  for (int i = ty; i < 32; i += 8)
    t[i][tx] = W[(by + i) * CDIM + bx + tx];
  __syncthreads();
  for (int i = ty; i < 32; i += 8)
    Wt[(bx + i) * CDIM + by + tx] = f2h(t[tx][i]);
}

__global__ void k_ecast(const float* __restrict__ eo, const float* __restrict__ ei,
                        unsigned short* __restrict__ ho, unsigned short* __restrict__ hi){
  int i = blockIdx.x * 256 + threadIdx.x;
  ho[i] = f2h(eo[i]);
  hi[i] = f2h(ei[i]);
}

// ---------------- bottleneck: grouped conv + BN + GELU (fp16 out), plus x->fp16 ----------------
__global__ __launch_bounds__(256) void k_bottleneck(
    const float* __restrict__ x,
    const float* __restrict__ cwo, const float* __restrict__ cbo,
    const float* __restrict__ go,  const float* __restrict__ bto,
    const float* __restrict__ mo,  const float* __restrict__ vo,
    const float* __restrict__ cwi, const float* __restrict__ cbi,
    const float* __restrict__ gi,  const float* __restrict__ bti,
    const float* __restrict__ mi,  const float* __restrict__ vi,
    unsigned short* __restrict__ x16,
    unsigned short* __restrict__ uo, unsigned short* __restrict__ ui)
{
  const int t = threadIdx.x;
  const int r0 = blockIdx.x * 8;
  float4 cwov = ((const float4*)cwo)[t];
  float4 cwiv = ((const float4*)cwi)[t];
  float sco = go[t] * rsqrtf(vo[t] + 1e-5f);
  float sho = bto[t] - mo[t] * sco;
  float cbov = cbo[t];
  float sci = gi[t] * rsqrtf(vi[t] + 1e-5f);
  float shi = bti[t] - mi[t] * sci;
  float cbiv = cbi[t];
  for (int r = 0; r < 8; ++r){
    int row = r0 + r;
    float4 xv = ((const float4*)x)[row * 256 + t];
    U4 xb; xb.x = f2h(xv.x); xb.y = f2h(xv.y); xb.z = f2h(xv.z); xb.w = f2h(xv.w);
    ((U4*)x16)[row * 256 + t] = xb;
    float h = xv.x*cwov.x + xv.y*cwov.y + xv.z*cwov.z + xv.w*cwov.w + cbov;
    h = h * sco + sho;
    float u = 0.5f * h * (1.0f + erff(h * 0.70710678118654752f));
    uo[row*BNC + t] = f2h(u);
    h = xv.x*cwiv.x + xv.y*cwiv.y + xv.z*cwiv.z + xv.w*cwiv.w + cbiv;
    h = h * sci + shi;
    u = 0.5f * h * (1.0f + erff(h * 0.70710678118654752f));
    ui[row*BNC + t] = f2h(u);
  }
}

// ---------------- expand GEMM (fp16): L = U@E^T + eb -> fp16 Lbuf ----------------
__global__ __launch_bounds__(256, 3) void k_expand(
    const unsigned short* __restrict__ u16, const unsigned short* __restrict__ e16,
    const float* __restrict__ eb, unsigned short* __restrict__ Lout)
{
  __shared__ alignas(16) char lds[3 * 16384];
  const int tid = threadIdx.x;
  const int lane = tid & 63, w = tid >> 6;
  const int wr = (w >> 1) * 64, wc = (w & 1) * 64;
  int id = blockIdx.x;
  int xcd = id & 7, slot = id >> 3;
  const int row0 = (xcd * 32 + (slot >> 3)) * 128;
  const int col0 = (slot & 7) * 128;
  f32x4 acc[4][4] = {};
  auto stage = [&](int h, int buf){
    char* b = lds + buf * 16384;
    stage_tile(u16 + row0 * BNC + h * 32, 512, b, tid);
    stage_tile(e16 + col0 * BNC + h * 32, 512, b + 8192, tid);
  };
  stage(0, 0);
  stage(1, 1);
  asm volatile("s_waitcnt vmcnt(4)" ::: "memory");
  __builtin_amdgcn_s_barrier();
  const unsigned lbase = ldsaddr(lds);
  const int NK = BNC / 32;
  for (int h = 0; h < NK; ++h){
    unsigned sl = lbase + (h % 3) * 16384;
    short8 af[4], bfr[4];
    #pragma unroll
    for (int m = 0; m < 4; ++m) af[m]  = dsr128(sl + frag_off(wr + m * 16 + (lane & 15), lane));
    #pragma unroll
    for (int n = 0; n < 4; ++n) bfr[n] = dsr128(sl + 8192 + frag_off(wc + n * 16 + (lane & 15), lane));
    if (h + 2 < NK) stage(h + 2, (h + 2) % 3);
    __builtin_amdgcn_s_barrier();
    asm volatile("s_waitcnt lgkmcnt(0)" ::: "memory");
    __builtin_amdgcn_sched_barrier(0);
    __builtin_amdgcn_s_setprio(1);
    #pragma unroll
    for (int m = 0; m < 4; ++m)
      #pragma unroll
      for (int n = 0; n < 4; ++n)
        acc[m][n] = __builtin_amdgcn_mfma_f32_16x16x32_f16(s2h(af[m]), s2h(bfr[n]), acc[m][n], 0, 0, 0);
    __builtin_amdgcn_s_setprio(0);
    if (h + 2 < NK)      asm volatile("s_waitcnt vmcnt(4)" ::: "memory");
    else if (h + 1 < NK) asm volatile("s_waitcnt vmcnt(0)" ::: "memory");
    __builtin_amdgcn_s_barrier();
  }
  #pragma unroll
  for (int n = 0; n < 4; ++n){
    int col = col0 + wc + n * 16 + (lane & 15);
    float ebv = eb[col];
    #pragma unroll
    for (int m = 0; m < 4; ++m){
      int row = row0 + wr + m * 16 + ((lane >> 4) << 2);
      #pragma unroll
      for (int r = 0; r < 4; ++r)
        Lout[(size_t)(row + r) * CDIM + col] = f2h(acc[m][n][r] + ebv);
    }
  }
}

// ---------------- softmax + top-128 threshold + sparse score (fp16 L) ----------------
template<bool WRITE_XS>
__global__ __launch_bounds__(256) void k_select(
    const unsigned short* __restrict__ Lg, const unsigned short* __restrict__ xg,
    unsigned short* __restrict__ obf)
{
  const int lane = threadIdx.x & 63;
  const int wv = threadIdx.x >> 6;
  int id = blockIdx.x;
  int xcd = id & 7, rest = id >> 3;
  int q = rest >> 5, b = rest & 31;
  const int row = (xcd * 32 + q) * 128 + b * 4 + wv;
  const unsigned short* Lr = Lg + (size_t)row * CDIM;
  unsigned short hv[16];
  #pragma unroll
  for (int c = 0; c < 2; ++c){
    short8 t8 = ((const short8*)Lr)[c * 64 + lane];
    #pragma unroll
    for (int j = 0; j < 8; ++j) hv[c*8+j] = (unsigned short)t8[j];
  }
  unsigned kx[16];
  #pragma unroll
  for (int j = 0; j < 16; ++j){
    unsigned u = hv[j];
    kx[j] = u ^ ((u & 0x8000u) ? 0xFFFFu : 0x8000u);
  }
  float v[16];
  #pragma unroll
  for (int j = 0; j < 16; ++j) v[j] = h2f(hv[j]);
  float M = v[0];
  #pragma unroll
  for (int j = 1; j < 16; ++j) M = fmaxf(M, v[j]);
  #pragma unroll
  for (int off = 32; off > 0; off >>= 1) M = fmaxf(M, __shfl_xor(M, off));
  float e[16];
  float S = 0.f;
  #pragma unroll
  for (int j = 0; j < 16; ++j){ e[j] = expf(v[j] - M); S += e[j]; }
  #pragma unroll
  for (int off = 32; off > 0; off >>= 1) S += __shfl_xor(S, off);
  unsigned pref = 0;
  for (int bit = 15; bit >= 0; --bit){
    unsigned cand = pref | (1u << bit);
    int c = 0;
    #pragma unroll
    for (int j = 0; j < 16; ++j)
      c += (int)__popcll(__ballot(kx[j] >= cand));
    if (c >= TOPK) pref = cand;
  }
  float invS = 1.0f / S;
  #pragma unroll
  for (int c = 0; c < 2; ++c){
    unsigned short o8[8];
    if (WRITE_XS){
      short8 xv = ((const short8*)(xg + (size_t)row * CDIM))[c * 64 + lane];
      #pragma unroll
      for (int j = 0; j < 8; ++j){
        int jj = c*8 + j;
        float scf = (kx[jj] >= pref) ? e[jj] * invS : 0.f;
        o8[j] = f2h(h2f((unsigned short)xv[j]) * scf);
      }
    } else {
      #pragma unroll
      for (int j = 0; j < 8; ++j){
        int jj = c*8 + j;
        float sc = (kx[jj] >= pref) ? e[jj] * invS : 0.f;
        o8[j] = f2h(sc);
      }
    }
    short8 st;
    #pragma unroll
    for (int j = 0; j < 8; ++j) st[j] = (short)o8[j];
    ((short8*)(obf + (size_t)row * CDIM))[c * 64 + lane] = st;
  }
}

// ---------------- main dual-A GEMM: 128x128, 3-slot lead-2, 2 blocks/CU ----------------
// (round-8 structure, fp16 operands; FROZEN — 5 structural variants benched, this wins.
//  LDS staging is the coalescer for the transposed fragment pattern: A-in-registers
//  regressed 175->313 us in round 10.)
__global__ __launch_bounds__(256, 2) void k_main(
    const unsigned short* __restrict__ x16, const unsigned short* __restrict__ xs16,
    const unsigned short* __restrict__ wt,  const unsigned short* __restrict__ so16,
    const float* __restrict__ bias, float* __restrict__ out)
{
  __shared__ alignas(16) char lds[3 * 24576];
  const int tid = threadIdx.x;
  const int lane = tid & 63, w = tid >> 6;
  const int wr = (w >> 1) * 64, wc = (w & 1) * 64;
  int id = blockIdx.x;
  int xcd = id & 7, sl = id >> 3;
  const int row0 = (xcd * 32 + (sl >> 3)) * 128;
  const int col0 = (sl & 7) * 128;
  f32x4 acc1[4][4] = {}, acc2[4][4] = {};
  auto stage = [&](int kt, int buf){
    char* b = lds + buf * 24576;
    stage_tile(x16  + row0 * CDIM + kt * 32, 2048, b, tid);
    stage_tile(xs16 + row0 * CDIM + kt * 32, 2048, b + 8192, tid);
    stage_tile(wt   + col0 * CDIM + kt * 32, 2048, b + 16384, tid);
  };
  stage(0, 0);
  stage(1, 1);
  asm volatile("s_waitcnt vmcnt(6)" ::: "memory");
  __builtin_amdgcn_s_barrier();
  const unsigned lbase = ldsaddr(lds);
  for (int kt = 0; kt < NKT; ++kt){
    const unsigned slr = lbase + (kt % 3) * 24576;
    short8 a1f[4], a2f[4], bfr[4];
    #pragma unroll
    for (int m = 0; m < 4; ++m){
      int fo = frag_off(wr + m * 16 + (lane & 15), lane);
      a1f[m] = dsr128(slr + fo);
      a2f[m] = dsr128(slr + 8192 + fo);
    }
    #pragma unroll
    for (int n = 0; n < 4; ++n)
      bfr[n] = dsr128(slr + 16384 + frag_off(wc + n * 16 + (lane & 15), lane));
    if (kt + 2 < NKT) stage(kt + 2, (kt + 2) % 3);
    asm volatile("s_waitcnt lgkmcnt(0)" ::: "memory");
    __builtin_amdgcn_sched_barrier(0);
    __builtin_amdgcn_s_setprio(1);
    #pragma unroll
    for (int m = 0; m < 4; ++m)
      #pragma unroll
      for (int n = 0; n < 4; ++n){
        acc1[m][n] = __builtin_amdgcn_mfma_f32_16x16x32_f16(s2h(a1f[m]), s2h(bfr[n]), acc1[m][n], 0, 0, 0);
        acc2[m][n] = __builtin_amdgcn_mfma_f32_16x16x32_f16(s2h(a2f[m]), s2h(bfr[n]), acc2[m][n], 0, 0, 0);
      }
    __builtin_amdgcn_s_setprio(0);
    if (kt + 2 < NKT)      asm volatile("s_waitcnt vmcnt(6)" ::: "memory");
    else if (kt + 1 < NKT) asm volatile("s_waitcnt vmcnt(0)" ::: "memory");
    __builtin_amdgcn_s_barrier();
  }
  #pragma unroll
  for (int n = 0; n < 4; ++n){
    int col = col0 + wc + n * 16 + (lane & 15);
    float bv = bias[col];
    #pragma unroll
    for (int m = 0; m < 4; ++m){
      int row = row0 + wr + m * 16 + ((lane >> 4) << 2);
      #pragma unroll
      for (int r = 0; r < 4; ++r){
        float so = h2f(so16[(size_t)(row + r) * CDIM + col]);
        out[(size_t)(row + r) * CDIM + col] = acc1[m][n][r] * so + acc2[m][n][r] + bv;
      }
    }
  }
}

extern "C" void kernel_launch(void* const* d_in, const int* in_sizes, int n_in,
                              void* d_out, int out_size, void* d_ws, size_t ws_size,
                              hipStream_t stream)
{
  const float* x    = (const float*)d_in[0];
  const float* W    = (const float*)d_in[1];
  const float* bias = (const float*)d_in[2];
  const float* cwo  = (const float*)d_in[3];
  const float* cbo  = (const float*)d_in[4];
  const float* bngo = (const float*)d_in[5];
  const float* bnbo = (const float*)d_in[6];
  const float* bnmo = (const float*)d_in[7];
  const float* bnvo = (const float*)d_in[8];
  const float* ewo  = (const float*)d_in[9];
  const float* ebo  = (const float*)d_in[10];
  const float* cwi  = (const float*)d_in[11];
  const float* cbi  = (const float*)d_in[12];
  const float* bngi = (const float*)d_in[13];
  const float* bnbi = (const float*)d_in[14];
  const float* bnmi = (const float*)d_in[15];
  const float* bnvi = (const float*)d_in[16];
  const float* ewi  = (const float*)d_in[17];
  const float* ebi  = (const float*)d_in[18];
  float* out = (float*)d_out;
  (void)in_sizes; (void)n_in; (void)out_size; (void)ws_size;

  char* ws = (char*)d_ws;
  size_t off = 0;
  auto alloc = [&](size_t bytes){ void* p = ws + off; off += (bytes + 255) & ~(size_t)255; return p; };
  unsigned short* x16  = (unsigned short*)alloc((size_t)NROWS * CDIM * 2);
  unsigned short* xs16 = (unsigned short*)alloc((size_t)NROWS * CDIM * 2);
  unsigned short* so16 = (unsigned short*)alloc((size_t)NROWS * CDIM * 2);
  unsigned short* Lbuf = (unsigned short*)alloc((size_t)NROWS * CDIM * 2);
  unsigned short* uo   = (unsigned short*)alloc((size_t)NROWS * BNC * 2);
  unsigned short* ui   = (unsigned short*)alloc((size_t)NROWS * BNC * 2);
  unsigned short* wtb  = (unsigned short*)alloc((size_t)CDIM * CDIM * 2);
  unsigned short* e16o = (unsigned short*)alloc((size_t)CDIM * BNC * 2);
  unsigned short* e16i = (unsigned short*)alloc((size_t)CDIM * BNC * 2);

  k_wt<<<dim3(32, 32), dim3(32, 8), 0, stream>>>(W, wtb);
  k_ecast<<<dim3(1024), dim3(256), 0, stream>>>(ewo, ewi, e16o, e16i);
  k_bottleneck<<<dim3(NROWS / 8), dim3(256), 0, stream>>>(
      x, cwo, cbo, bngo, bnbo, bnmo, bnvo,
      cwi, cbi, bngi, bnbi, bnmi, bnvi, x16, uo, ui);
  k_expand<<<dim3(2048), dim3(256), 0, stream>>>(uo, e16o, ebo, Lbuf);
  k_select<false><<<dim3(NROWS / 4), dim3(256), 0, stream>>>(Lbuf, nullptr, so16);
  k_expand<<<dim3(2048), dim3(256), 0, stream>>>(ui, e16i, ebi, Lbuf);
  k_select<true><<<dim3(NROWS / 4), dim3(256), 0, stream>>>(Lbuf, x16, xs16);
  k_main<<<dim3(2048), dim3(256), 0, stream>>>(x16, xs16, wtb, so16, bias, out);
}